// Round 12
// baseline (155.270 us; speedup 1.0000x reference)
//
#include <hip/hip_runtime.h>

#define BB 8
#define NN 2048
#define IND 128
#define OUTD 64
#define ALPHA 0.2f

typedef __attribute__((ext_vector_type(8))) short bf16x8;
typedef __attribute__((ext_vector_type(4))) float f32x4;
typedef __attribute__((ext_vector_type(4))) int i32x4;
typedef unsigned int u32;

// ---------------- K1: h = x@W -> h_T (bf16 hi/lo, [B][64][2048]), si, sj ----
__global__ __launch_bounds__(256) void k1_hproj(const float* __restrict__ x,
                                                const float* __restrict__ W,
                                                const float* __restrict__ a,
                                                short* __restrict__ hT_hi,
                                                short* __restrict__ hT_lo,
                                                float* __restrict__ si,
                                                float* __restrict__ sj) {
    __shared__ float Wl[IND * OUTD];     // 32 KB
    __shared__ float xl[16][IND];        // 8 KB
    __shared__ float tile[16][OUTD + 1]; // h tile for transpose (pad 65)
    int t = threadIdx.x, lane = t & 63, wave = t >> 6;

    const float4* W4 = (const float4*)W;
    float4* Wl4 = (float4*)Wl;
    #pragma unroll
    for (int q = 0; q < 8; ++q) Wl4[t + q * 256] = W4[t + q * 256];

    int row0 = blockIdx.x * 16;                    // global row in [0, B*N)
    const float4* x4 = (const float4*)(x + (size_t)row0 * IND);
    float4* xl4 = (float4*)&xl[0][0];
    xl4[t] = x4[t];
    xl4[t + 256] = x4[t + 256];
    __syncthreads();

    float a1v = a[lane];
    float a2v = a[OUTD + lane];

    float acc[4] = {0.f, 0.f, 0.f, 0.f};
    int rbase = wave * 4;
    for (int k = 0; k < IND; k += 4) {
        float4 xv0 = *(const float4*)&xl[rbase + 0][k];
        float4 xv1 = *(const float4*)&xl[rbase + 1][k];
        float4 xv2 = *(const float4*)&xl[rbase + 2][k];
        float4 xv3 = *(const float4*)&xl[rbase + 3][k];
        #pragma unroll
        for (int q = 0; q < 4; ++q) {
            float w = Wl[(k + q) * OUTD + lane];
            acc[0] = fmaf(((const float*)&xv0)[q], w, acc[0]);
            acc[1] = fmaf(((const float*)&xv1)[q], w, acc[1]);
            acc[2] = fmaf(((const float*)&xv2)[q], w, acc[2]);
            acc[3] = fmaf(((const float*)&xv3)[q], w, acc[3]);
        }
    }
    #pragma unroll
    for (int rr = 0; rr < 4; ++rr) {
        size_t grow = (size_t)row0 + rbase + rr;
        tile[rbase + rr][lane] = acc[rr];
        float v1 = acc[rr] * a1v;
        float v2 = acc[rr] * a2v;
        #pragma unroll
        for (int o = 32; o; o >>= 1) {
            v1 += __shfl_xor(v1, o);
            v2 += __shfl_xor(v2, o);
        }
        if (lane == 0) { si[grow] = v1; sj[grow] = v2; }
    }
    __syncthreads();

    // transpose + bf16 hi/lo split: thread t -> d = t>>2, k-quad = (t&3)*4
    int d = t >> 2, kq = (t & 3) * 4;
    int b = row0 >> 11;                // batch
    int krow = (row0 & (NN - 1)) + kq; // k index within batch
    float v0 = tile[kq + 0][d], v1 = tile[kq + 1][d];
    float v2 = tile[kq + 2][d], v3 = tile[kq + 3][d];
    u32 b0 = __float_as_uint(v0), b1 = __float_as_uint(v1);
    u32 b2 = __float_as_uint(v2), b3 = __float_as_uint(v3);
    u32 h0 = b0 & 0xffff0000u, h1 = b1 & 0xffff0000u;
    u32 h2 = b2 & 0xffff0000u, h3 = b3 & 0xffff0000u;
    float l0 = v0 - __uint_as_float(h0), l1 = v1 - __uint_as_float(h1);
    float l2 = v2 - __uint_as_float(h2), l3 = v3 - __uint_as_float(h3);
    uint2 hi2, lo2;
    hi2.x = (b0 >> 16) | h1;
    hi2.y = (b2 >> 16) | h3;
    lo2.x = (__float_as_uint(l0) >> 16) | (__float_as_uint(l1) & 0xffff0000u);
    lo2.y = (__float_as_uint(l2) >> 16) | (__float_as_uint(l3) & 0xffff0000u);
    size_t off = ((size_t)b * OUTD + d) * NN + krow;   // in shorts (8B aligned)
    *(uint2*)(hT_hi + off) = hi2;
    *(uint2*)(hT_lo + off) = lo2;
}

// ---------------- K23: fused mask + attention writer (copy-shaped). --------
// One wave owns 2 rows (same batch -> shared sv). 16 NT adj loads up-front,
// masks+sums in registers, wave-reduce, invS+mask stores, then recompute p
// and NT-store both attention rows. No LDS, no barriers; reads and writes
// interleave so both HBM directions stay busy.
__global__ __launch_bounds__(256) void k23(const int* __restrict__ adj,
                                           const float* __restrict__ si,
                                           const float* __restrict__ sj,
                                           float* __restrict__ invS,
                                           unsigned char* __restrict__ mask,
                                           float* __restrict__ attn) {
    int t = threadIdx.x, lane = t & 63, w = t >> 6;
    int rp = blockIdx.x * 4 + w;       // row pair, [0, 8192)
    int row0 = rp * 2;
    int b = row0 >> 11;
    const i32x4* a0 = (const i32x4*)(adj + (size_t)row0 * NN);
    const i32x4* a1 = (const i32x4*)(adj + (size_t)(row0 + 1) * NN);
    const f32x4* sjb4 = (const f32x4*)(sj + ((size_t)b << 11));

    i32x4 av0[8], av1[8];
    f32x4 sv[8];
    #pragma unroll
    for (int q = 0; q < 8; ++q) av0[q] = __builtin_nontemporal_load(&a0[q * 64 + lane]);
    #pragma unroll
    for (int q = 0; q < 8; ++q) av1[q] = __builtin_nontemporal_load(&a1[q * 64 + lane]);
    #pragma unroll
    for (int q = 0; q < 8; ++q) sv[q] = sjb4[q * 64 + lane];
    float si0 = si[row0], si1 = si[row0 + 1];

    u32 nib0 = 0, nib1 = 0;
    float sum0 = 0.f, sum1 = 0.f;
    #pragma unroll
    for (int q = 0; q < 8; ++q) {
        f32x4 s = sv[q];
        float e, pe;
        i32x4 A = av0[q];
        e = si0 + s.x; e = e > 0.f ? e : ALPHA * e; pe = __expf(e);
        if (A.x > 0) { nib0 |= 1u << (q * 4 + 0); sum0 += pe; }
        e = si0 + s.y; e = e > 0.f ? e : ALPHA * e; pe = __expf(e);
        if (A.y > 0) { nib0 |= 1u << (q * 4 + 1); sum0 += pe; }
        e = si0 + s.z; e = e > 0.f ? e : ALPHA * e; pe = __expf(e);
        if (A.z > 0) { nib0 |= 1u << (q * 4 + 2); sum0 += pe; }
        e = si0 + s.w; e = e > 0.f ? e : ALPHA * e; pe = __expf(e);
        if (A.w > 0) { nib0 |= 1u << (q * 4 + 3); sum0 += pe; }
        i32x4 B = av1[q];
        e = si1 + s.x; e = e > 0.f ? e : ALPHA * e; pe = __expf(e);
        if (B.x > 0) { nib1 |= 1u << (q * 4 + 0); sum1 += pe; }
        e = si1 + s.y; e = e > 0.f ? e : ALPHA * e; pe = __expf(e);
        if (B.y > 0) { nib1 |= 1u << (q * 4 + 1); sum1 += pe; }
        e = si1 + s.z; e = e > 0.f ? e : ALPHA * e; pe = __expf(e);
        if (B.z > 0) { nib1 |= 1u << (q * 4 + 2); sum1 += pe; }
        e = si1 + s.w; e = e > 0.f ? e : ALPHA * e; pe = __expf(e);
        if (B.w > 0) { nib1 |= 1u << (q * 4 + 3); sum1 += pe; }
    }
    #pragma unroll
    for (int o = 32; o; o >>= 1) {
        sum0 += __shfl_xor(sum0, o);
        sum1 += __shfl_xor(sum1, o);
    }
    float inv0 = sum0 > 0.f ? 1.0f / sum0 : 0.f;
    float inv1 = sum1 > 0.f ? 1.0f / sum1 : 0.f;
    if (lane == 0) { invS[row0] = inv0; invS[row0 + 1] = inv1; }

    // mask bytes: byte (q*32 + lane/2) covers j [8k, 8k+8)
    #pragma unroll
    for (int q = 0; q < 8; ++q) {
        u32 n0 = (nib0 >> (q * 4)) & 0xFu, n1 = (nib1 >> (q * 4)) & 0xFu;
        u32 p0 = (u32)__shfl_xor((int)n0, 1), p1 = (u32)__shfl_xor((int)n1, 1);
        if (!(lane & 1)) {
            mask[(size_t)row0 * 256 + q * 32 + (lane >> 1)] = (unsigned char)(n0 | (p0 << 4));
            mask[(size_t)(row0 + 1) * 256 + q * 32 + (lane >> 1)] = (unsigned char)(n1 | (p1 << 4));
        }
    }

    // attention rows (recompute exp; NT stores, 1KB/wave-instr)
    float* o0 = attn + (size_t)row0 * NN;
    float* o1 = attn + (size_t)(row0 + 1) * NN;
    #pragma unroll
    for (int q = 0; q < 8; ++q) {
        f32x4 s = sv[q];
        u32 n0 = nib0 >> (q * 4), n1 = nib1 >> (q * 4);
        f32x4 pv;
        float e;
        e = si0 + s.x; e = e > 0.f ? e : ALPHA * e;
        pv.x = (n0 & 1u) ? __expf(e) * inv0 : 0.f;
        e = si0 + s.y; e = e > 0.f ? e : ALPHA * e;
        pv.y = (n0 & 2u) ? __expf(e) * inv0 : 0.f;
        e = si0 + s.z; e = e > 0.f ? e : ALPHA * e;
        pv.z = (n0 & 4u) ? __expf(e) * inv0 : 0.f;
        e = si0 + s.w; e = e > 0.f ? e : ALPHA * e;
        pv.w = (n0 & 8u) ? __expf(e) * inv0 : 0.f;
        __builtin_nontemporal_store(pv, (f32x4*)(o0 + q * 256 + lane * 4));
        e = si1 + s.x; e = e > 0.f ? e : ALPHA * e;
        pv.x = (n1 & 1u) ? __expf(e) * inv1 : 0.f;
        e = si1 + s.y; e = e > 0.f ? e : ALPHA * e;
        pv.y = (n1 & 2u) ? __expf(e) * inv1 : 0.f;
        e = si1 + s.z; e = e > 0.f ? e : ALPHA * e;
        pv.z = (n1 & 4u) ? __expf(e) * inv1 : 0.f;
        e = si1 + s.w; e = e > 0.f ? e : ALPHA * e;
        pv.w = (n1 & 8u) ? __expf(e) * inv1 : 0.f;
        __builtin_nontemporal_store(pv, (f32x4*)(o1 + q * 256 + lane * 4));
    }
}

// ---------------- K4: MFMA PV. p recomputed in-register from mask. ---------
__global__ __launch_bounds__(256) void k4_pv(const unsigned char* __restrict__ mask,
                                             const float* __restrict__ si,
                                             const float* __restrict__ sj,
                                             const float* __restrict__ invS,
                                             const short* __restrict__ hT_hi,
                                             const short* __restrict__ hT_lo,
                                             float* __restrict__ hp) {
    __shared__ f32x4 red[4][4][64];   // 16 KB

    int t = threadIdx.x, lane = t & 63, w = t >> 6;
    int bk = blockIdx.x;              // 1024 tiles
    int b = bk >> 7;
    int i0 = (bk & 127) * 16;
    size_t rowbase = (size_t)b * NN + i0;
    const float* sjb = sj + (size_t)b * NN;

    int m = lane & 15, g = lane >> 4;
    float si_m = si[rowbase + m];
    float inv_m = invS[rowbase + m];
    const unsigned char* mrow = mask + (rowbase + m) * 256;
    const short* bh0 = hT_hi + ((size_t)b * OUTD + m) * NN;
    const short* bl0 = hT_lo + ((size_t)b * OUTD + m) * NN;

    f32x4 acc[4];
    #pragma unroll
    for (int tt = 0; tt < 4; ++tt) acc[tt] = (f32x4){0.f, 0.f, 0.f, 0.f};

    #pragma unroll 2
    for (int step = 0; step < 16; ++step) {
        int kk = w * 512 + step * 32;
        int c0 = kk + g * 8;
        unsigned mb = mrow[(kk >> 3) + g];
        f32x4 s0 = *(const f32x4*)(sjb + c0);
        f32x4 s1 = *(const f32x4*)(sjb + c0 + 4);
        float sv[8] = {s0.x, s0.y, s0.z, s0.w, s1.x, s1.y, s1.z, s1.w};
        float p[8];
        #pragma unroll
        for (int q = 0; q < 8; ++q) {
            float e = si_m + sv[q];
            e = e > 0.f ? e : ALPHA * e;
            float pe = __expf(e) * inv_m;
            p[q] = ((mb >> q) & 1u) ? pe : 0.f;
        }

        union { bf16x8 v; u32 u[4]; } ph, pl;
        #pragma unroll
        for (int q = 0; q < 4; ++q) {
            u32 c0u = __float_as_uint(p[2 * q]), c1u = __float_as_uint(p[2 * q + 1]);
            u32 t0 = c0u & 0xffff0000u, t1 = c1u & 0xffff0000u;
            float d0 = p[2 * q] - __uint_as_float(t0);
            float d1 = p[2 * q + 1] - __uint_as_float(t1);
            ph.u[q] = (c0u >> 16) | t1;
            pl.u[q] = (__float_as_uint(d0) >> 16) | (__float_as_uint(d1) & 0xffff0000u);
        }

        #pragma unroll
        for (int tt = 0; tt < 4; ++tt) {
            bf16x8 bh = *(const bf16x8*)(bh0 + (size_t)tt * 16 * NN + c0);
            bf16x8 bl = *(const bf16x8*)(bl0 + (size_t)tt * 16 * NN + c0);
            acc[tt] = __builtin_amdgcn_mfma_f32_16x16x32_bf16(ph.v, bh, acc[tt], 0, 0, 0);
            acc[tt] = __builtin_amdgcn_mfma_f32_16x16x32_bf16(ph.v, bl, acc[tt], 0, 0, 0);
            acc[tt] = __builtin_amdgcn_mfma_f32_16x16x32_bf16(pl.v, bh, acc[tt], 0, 0, 0);
        }
    }

    // ---- cross-wave reduce of D (16 rows x 64 dims) ----
    #pragma unroll
    for (int tt = 0; tt < 4; ++tt) red[w][tt][lane] = acc[tt];
    __syncthreads();

    for (int idx = t; idx < 16 * OUTD; idx += 256) {
        int row = idx >> 6, n = idx & 63;
        int ln = (row >> 2) * 16 + (n & 15);
        int reg = row & 3;
        float v = ((const float*)&red[0][n >> 4][ln])[reg]
                + ((const float*)&red[1][n >> 4][ln])[reg]
                + ((const float*)&red[2][n >> 4][ln])[reg]
                + ((const float*)&red[3][n >> 4][ln])[reg];
        hp[(rowbase + row) * OUTD + n] = v;
    }
}

extern "C" void kernel_launch(void* const* d_in, const int* in_sizes, int n_in,
                              void* d_out, int out_size, void* d_ws, size_t ws_size,
                              hipStream_t stream) {
    const float* x   = (const float*)d_in[0];
    const int*   adj = (const int*)d_in[1];
    const float* W   = (const float*)d_in[2];
    const float* a   = (const float*)d_in[3];

    float* out  = (float*)d_out;
    float* hp   = out;                                  // (B,N,OUT)
    float* attn = out + (size_t)BB * NN * OUTD;         // (B,N,N)

    char* ws = (char*)d_ws;
    short* hT_hi = (short*)ws;                           // 2 MB
    short* hT_lo = hT_hi + (size_t)BB * OUTD * NN;       // 2 MB
    float* si    = (float*)(hT_lo + (size_t)BB * OUTD * NN);
    float* sj    = si + (size_t)BB * NN;
    float* invS  = sj + (size_t)BB * NN;
    unsigned char* mask = (unsigned char*)(invS + (size_t)BB * NN);  // 4 MB

    k1_hproj<<<BB * NN / 16, 256, 0, stream>>>(x, W, a, hT_hi, hT_lo, si, sj);
    k23<<<BB * NN / 8, 256, 0, stream>>>(adj, si, sj, invS, mask, attn);
    k4_pv<<<BB * NN / 16, 256, 0, stream>>>(mask, si, sj, invS, hT_hi, hT_lo, hp);
}

// Round 13
// 147.773 us; speedup vs baseline: 1.0507x; 1.0507x over previous
//
#include <hip/hip_runtime.h>

#define BB 8
#define NN 2048
#define IND 128
#define OUTD 64
#define ALPHA 0.2f

typedef __attribute__((ext_vector_type(8))) short bf16x8;
typedef __attribute__((ext_vector_type(4))) float f32x4;
typedef __attribute__((ext_vector_type(4))) int i32x4;
typedef unsigned int u32;

// ---------------- K1: h = x@W -> h_T (bf16 hi/lo, [B][64][2048]), si, sj ----
__global__ __launch_bounds__(256) void k1_hproj(const float* __restrict__ x,
                                                const float* __restrict__ W,
                                                const float* __restrict__ a,
                                                short* __restrict__ hT_hi,
                                                short* __restrict__ hT_lo,
                                                float* __restrict__ si,
                                                float* __restrict__ sj) {
    __shared__ float Wl[IND * OUTD];     // 32 KB
    __shared__ float xl[16][IND];        // 8 KB
    __shared__ float tile[16][OUTD + 1]; // h tile for transpose (pad 65)
    int t = threadIdx.x, lane = t & 63, wave = t >> 6;

    const float4* W4 = (const float4*)W;
    float4* Wl4 = (float4*)Wl;
    #pragma unroll
    for (int q = 0; q < 8; ++q) Wl4[t + q * 256] = W4[t + q * 256];

    int row0 = blockIdx.x * 16;                    // global row in [0, B*N)
    const float4* x4 = (const float4*)(x + (size_t)row0 * IND);
    float4* xl4 = (float4*)&xl[0][0];
    xl4[t] = x4[t];
    xl4[t + 256] = x4[t + 256];
    __syncthreads();

    float a1v = a[lane];
    float a2v = a[OUTD + lane];

    float acc[4] = {0.f, 0.f, 0.f, 0.f};
    int rbase = wave * 4;
    for (int k = 0; k < IND; k += 4) {
        float4 xv0 = *(const float4*)&xl[rbase + 0][k];
        float4 xv1 = *(const float4*)&xl[rbase + 1][k];
        float4 xv2 = *(const float4*)&xl[rbase + 2][k];
        float4 xv3 = *(const float4*)&xl[rbase + 3][k];
        #pragma unroll
        for (int q = 0; q < 4; ++q) {
            float w = Wl[(k + q) * OUTD + lane];
            acc[0] = fmaf(((const float*)&xv0)[q], w, acc[0]);
            acc[1] = fmaf(((const float*)&xv1)[q], w, acc[1]);
            acc[2] = fmaf(((const float*)&xv2)[q], w, acc[2]);
            acc[3] = fmaf(((const float*)&xv3)[q], w, acc[3]);
        }
    }
    #pragma unroll
    for (int rr = 0; rr < 4; ++rr) {
        size_t grow = (size_t)row0 + rbase + rr;
        tile[rbase + rr][lane] = acc[rr];
        float v1 = acc[rr] * a1v;
        float v2 = acc[rr] * a2v;
        #pragma unroll
        for (int o = 32; o; o >>= 1) {
            v1 += __shfl_xor(v1, o);
            v2 += __shfl_xor(v2, o);
        }
        if (lane == 0) { si[grow] = v1; sj[grow] = v2; }
    }
    __syncthreads();

    // transpose + bf16 hi/lo split: thread t -> d = t>>2, k-quad = (t&3)*4
    int d = t >> 2, kq = (t & 3) * 4;
    int b = row0 >> 11;                // batch
    int krow = (row0 & (NN - 1)) + kq; // k index within batch
    float v0 = tile[kq + 0][d], v1 = tile[kq + 1][d];
    float v2 = tile[kq + 2][d], v3 = tile[kq + 3][d];
    u32 b0 = __float_as_uint(v0), b1 = __float_as_uint(v1);
    u32 b2 = __float_as_uint(v2), b3 = __float_as_uint(v3);
    u32 h0 = b0 & 0xffff0000u, h1 = b1 & 0xffff0000u;
    u32 h2 = b2 & 0xffff0000u, h3 = b3 & 0xffff0000u;
    float l0 = v0 - __uint_as_float(h0), l1 = v1 - __uint_as_float(h1);
    float l2 = v2 - __uint_as_float(h2), l3 = v3 - __uint_as_float(h3);
    uint2 hi2, lo2;
    hi2.x = (b0 >> 16) | h1;
    hi2.y = (b2 >> 16) | h3;
    lo2.x = (__float_as_uint(l0) >> 16) | (__float_as_uint(l1) & 0xffff0000u);
    lo2.y = (__float_as_uint(l2) >> 16) | (__float_as_uint(l3) & 0xffff0000u);
    size_t off = ((size_t)b * OUTD + d) * NN + krow;   // in shorts (8B aligned)
    *(uint2*)(hT_hi + off) = hi2;
    *(uint2*)(hT_lo + off) = lo2;
}

// ---------------- K23: pipelined mask + attention writer (copy-shaped) -----
// Wave owns 4 rows. Steady state per row r:
//   waitcnt -> consume adj buf (nib+sum exp pass) -> ISSUE row r+1 adj loads
//   -> shuffle-reduce -> invS+mask stores -> 8 NT attn stores (exp recompute).
// Row r+1's reads are in flight during row r's store phase: reads and writes
// co-issue continuously per wave. No LDS, no barriers. Normal adj loads
// (cacheable -> partial L3 retention across replays, cf. R7 FETCH=82MB).
__global__ __launch_bounds__(256) void k23(const int* __restrict__ adj,
                                           const float* __restrict__ si,
                                           const float* __restrict__ sj,
                                           float* __restrict__ invS,
                                           unsigned char* __restrict__ mask,
                                           float* __restrict__ attn) {
    int t = threadIdx.x, lane = t & 63, w = t >> 6;
    int row0 = (blockIdx.x * 4 + w) * 4;     // wave owns rows row0..row0+3
    int b = row0 >> 11;
    const f32x4* sjb4 = (const f32x4*)(sj + ((size_t)b << 11));

    f32x4 sv[8];
    #pragma unroll
    for (int q = 0; q < 8; ++q) sv[q] = sjb4[q * 64 + lane];

    i32x4 buf[8];
    {
        const i32x4* a0 = (const i32x4*)(adj + (size_t)row0 * NN);
        #pragma unroll
        for (int q = 0; q < 8; ++q) buf[q] = a0[q * 64 + lane];
    }

    #pragma unroll
    for (int r = 0; r < 4; ++r) {
        int row = row0 + r;
        float s_i = si[row];

        // ---- consume buf: nib bits + exp sum ----
        u32 nib = 0;
        float sum = 0.f;
        #pragma unroll
        for (int q = 0; q < 8; ++q) {
            i32x4 A = buf[q];
            f32x4 s = sv[q];
            float e, pe;
            e = s_i + s.x; e = e > 0.f ? e : ALPHA * e; pe = __expf(e);
            if (A.x > 0) { nib |= 1u << (q * 4 + 0); sum += pe; }
            e = s_i + s.y; e = e > 0.f ? e : ALPHA * e; pe = __expf(e);
            if (A.y > 0) { nib |= 1u << (q * 4 + 1); sum += pe; }
            e = s_i + s.z; e = e > 0.f ? e : ALPHA * e; pe = __expf(e);
            if (A.z > 0) { nib |= 1u << (q * 4 + 2); sum += pe; }
            e = s_i + s.w; e = e > 0.f ? e : ALPHA * e; pe = __expf(e);
            if (A.w > 0) { nib |= 1u << (q * 4 + 3); sum += pe; }
        }

        // ---- buf free: issue next row's adj loads (fly under stores) ----
        if (r < 3) {
            const i32x4* an = (const i32x4*)(adj + (size_t)(row + 1) * NN);
            #pragma unroll
            for (int q = 0; q < 8; ++q) buf[q] = an[q * 64 + lane];
        }

        // ---- reduce + invS ----
        #pragma unroll
        for (int o = 32; o; o >>= 1) sum += __shfl_xor(sum, o);
        float inv = sum > 0.f ? 1.0f / sum : 0.f;
        if (lane == 0) invS[row] = inv;

        // ---- mask bytes: byte (q*32 + lane/2) covers j [8k, 8k+8) ----
        #pragma unroll
        for (int q = 0; q < 8; ++q) {
            u32 n0 = (nib >> (q * 4)) & 0xFu;
            u32 pn = (u32)__shfl_xor((int)n0, 1);
            if (!(lane & 1))
                mask[(size_t)row * 256 + q * 32 + (lane >> 1)] =
                    (unsigned char)(n0 | (pn << 4));
        }

        // ---- attn row: 8 NT f32x4 stores, exp recompute ----
        float* orow = attn + (size_t)row * NN;
        #pragma unroll
        for (int q = 0; q < 8; ++q) {
            f32x4 s = sv[q];
            u32 n = nib >> (q * 4);
            f32x4 pv;
            float e;
            e = s_i + s.x; e = e > 0.f ? e : ALPHA * e;
            pv.x = (n & 1u) ? __expf(e) * inv : 0.f;
            e = s_i + s.y; e = e > 0.f ? e : ALPHA * e;
            pv.y = (n & 2u) ? __expf(e) * inv : 0.f;
            e = s_i + s.z; e = e > 0.f ? e : ALPHA * e;
            pv.z = (n & 4u) ? __expf(e) * inv : 0.f;
            e = s_i + s.w; e = e > 0.f ? e : ALPHA * e;
            pv.w = (n & 8u) ? __expf(e) * inv : 0.f;
            __builtin_nontemporal_store(pv, (f32x4*)(orow + q * 256 + lane * 4));
        }
    }
}

// ---------------- K4: MFMA PV. p recomputed in-register from mask. ---------
__global__ __launch_bounds__(256) void k4_pv(const unsigned char* __restrict__ mask,
                                             const float* __restrict__ si,
                                             const float* __restrict__ sj,
                                             const float* __restrict__ invS,
                                             const short* __restrict__ hT_hi,
                                             const short* __restrict__ hT_lo,
                                             float* __restrict__ hp) {
    __shared__ f32x4 red[4][4][64];   // 16 KB

    int t = threadIdx.x, lane = t & 63, w = t >> 6;
    int bk = blockIdx.x;              // 1024 tiles
    int b = bk >> 7;
    int i0 = (bk & 127) * 16;
    size_t rowbase = (size_t)b * NN + i0;
    const float* sjb = sj + (size_t)b * NN;

    int m = lane & 15, g = lane >> 4;
    float si_m = si[rowbase + m];
    float inv_m = invS[rowbase + m];
    const unsigned char* mrow = mask + (rowbase + m) * 256;
    const short* bh0 = hT_hi + ((size_t)b * OUTD + m) * NN;
    const short* bl0 = hT_lo + ((size_t)b * OUTD + m) * NN;

    f32x4 acc[4];
    #pragma unroll
    for (int tt = 0; tt < 4; ++tt) acc[tt] = (f32x4){0.f, 0.f, 0.f, 0.f};

    #pragma unroll 2
    for (int step = 0; step < 16; ++step) {
        int kk = w * 512 + step * 32;
        int c0 = kk + g * 8;
        unsigned mb = mrow[(kk >> 3) + g];
        f32x4 s0 = *(const f32x4*)(sjb + c0);
        f32x4 s1 = *(const f32x4*)(sjb + c0 + 4);
        float sv[8] = {s0.x, s0.y, s0.z, s0.w, s1.x, s1.y, s1.z, s1.w};
        float p[8];
        #pragma unroll
        for (int q = 0; q < 8; ++q) {
            float e = si_m + sv[q];
            e = e > 0.f ? e : ALPHA * e;
            float pe = __expf(e) * inv_m;
            p[q] = ((mb >> q) & 1u) ? pe : 0.f;
        }

        union { bf16x8 v; u32 u[4]; } ph, pl;
        #pragma unroll
        for (int q = 0; q < 4; ++q) {
            u32 c0u = __float_as_uint(p[2 * q]), c1u = __float_as_uint(p[2 * q + 1]);
            u32 t0 = c0u & 0xffff0000u, t1 = c1u & 0xffff0000u;
            float d0 = p[2 * q] - __uint_as_float(t0);
            float d1 = p[2 * q + 1] - __uint_as_float(t1);
            ph.u[q] = (c0u >> 16) | t1;
            pl.u[q] = (__float_as_uint(d0) >> 16) | (__float_as_uint(d1) & 0xffff0000u);
        }

        #pragma unroll
        for (int tt = 0; tt < 4; ++tt) {
            bf16x8 bh = *(const bf16x8*)(bh0 + (size_t)tt * 16 * NN + c0);
            bf16x8 bl = *(const bf16x8*)(bl0 + (size_t)tt * 16 * NN + c0);
            acc[tt] = __builtin_amdgcn_mfma_f32_16x16x32_bf16(ph.v, bh, acc[tt], 0, 0, 0);
            acc[tt] = __builtin_amdgcn_mfma_f32_16x16x32_bf16(ph.v, bl, acc[tt], 0, 0, 0);
            acc[tt] = __builtin_amdgcn_mfma_f32_16x16x32_bf16(pl.v, bh, acc[tt], 0, 0, 0);
        }
    }

    // ---- cross-wave reduce of D (16 rows x 64 dims) ----
    #pragma unroll
    for (int tt = 0; tt < 4; ++tt) red[w][tt][lane] = acc[tt];
    __syncthreads();

    for (int idx = t; idx < 16 * OUTD; idx += 256) {
        int row = idx >> 6, n = idx & 63;
        int ln = (row >> 2) * 16 + (n & 15);
        int reg = row & 3;
        float v = ((const float*)&red[0][n >> 4][ln])[reg]
                + ((const float*)&red[1][n >> 4][ln])[reg]
                + ((const float*)&red[2][n >> 4][ln])[reg]
                + ((const float*)&red[3][n >> 4][ln])[reg];
        hp[(rowbase + row) * OUTD + n] = v;
    }
}

extern "C" void kernel_launch(void* const* d_in, const int* in_sizes, int n_in,
                              void* d_out, int out_size, void* d_ws, size_t ws_size,
                              hipStream_t stream) {
    const float* x   = (const float*)d_in[0];
    const int*   adj = (const int*)d_in[1];
    const float* W   = (const float*)d_in[2];
    const float* a   = (const float*)d_in[3];

    float* out  = (float*)d_out;
    float* hp   = out;                                  // (B,N,OUT)
    float* attn = out + (size_t)BB * NN * OUTD;         // (B,N,N)

    char* ws = (char*)d_ws;
    short* hT_hi = (short*)ws;                           // 2 MB
    short* hT_lo = hT_hi + (size_t)BB * OUTD * NN;       // 2 MB
    float* si    = (float*)(hT_lo + (size_t)BB * OUTD * NN);
    float* sj    = si + (size_t)BB * NN;
    float* invS  = sj + (size_t)BB * NN;
    unsigned char* mask = (unsigned char*)(invS + (size_t)BB * NN);  // 4 MB

    k1_hproj<<<BB * NN / 16, 256, 0, stream>>>(x, W, a, hT_hi, hT_lo, si, sj);
    k23<<<BB * NN / 16, 256, 0, stream>>>(adj, si, sj, invS, mask, attn);
    k4_pv<<<BB * NN / 16, 256, 0, stream>>>(mask, si, sj, invS, hT_hi, hT_lo, hp);
}